// Round 3
// baseline (93.432 us; speedup 1.0000x reference)
//
#include <hip/hip_runtime.h>
#include <hip/hip_cooperative_groups.h>
#include <math.h>

namespace cg = cooperative_groups;

// B=8, N=20, H=W=512. loss = sum(bce*valid)/cnt where the last point n with
// exp(-d2/(2*5^2)) > 0.1 (<=> d2 < 50*ln10) defines the per-pixel label.

#define R2_THRESH 115.12925464970229f
#define HW 512
#define NPTS 20
#define ROWS_PER_BLOCK 8
#define NBLOCKS (8 * (HW / ROWS_PER_BLOCK))   // 512 blocks = 2/CU -> coop-resident

__global__ __launch_bounds__(256)
void pce_coop_kernel(const float* __restrict__ y_pred,
                     const int* __restrict__ point_labels,
                     const float* __restrict__ point_coords,
                     float* __restrict__ ws,
                     float* __restrict__ out) {
    const int b     = blockIdx.x >> 6;        // 64 row-chunks per batch
    const int chunk = blockIdx.x & 63;
    const int y0    = chunk * ROWS_PER_BLOCK;
    const int tid   = threadIdx.x;
    const int r     = tid >> 5;               // 8 rows, 32 lanes each
    const int lane  = tid & 31;

    __shared__ float s_xc[ROWS_PER_BLOCK][NPTS];
    __shared__ float s_lim[ROWS_PER_BLOCK][NPTS];
    __shared__ float s_lab[ROWS_PER_BLOCK][NPTS];

    // ---- parallel setup: thread (r, n=lane<20) tests point n on row y0+r ----
    float xlo = INFINITY, xhi = -INFINITY;
    if (lane < NPTS) {
        const int n = lane;
        float yc  = point_coords[b * (NPTS * 2) + n * 2 + 0] * (float)HW;
        float xc  = point_coords[b * (NPTS * 2) + n * 2 + 1] * (float)HW;
        float dy  = (float)(y0 + r) - yc;
        float lim = R2_THRESH - dy * dy;      // same formulation as R1/R2 (absmax 0)
        s_xc[r][n]  = xc;
        s_lim[r][n] = lim;                    // lim<=0 -> dx*dx<lim never true
        s_lab[r][n] = (float)point_labels[b * NPTS + n];
        if (lim > 0.0f) {
            float s = sqrtf(lim);
            xlo = xc - s;
            xhi = xc + s;
        }
    }
    // bbox min/max across the 32-lane row group
    #pragma unroll
    for (int off = 16; off > 0; off >>= 1) {
        xlo = fminf(xlo, __shfl_xor(xlo, off, 32));
        xhi = fmaxf(xhi, __shfl_xor(xhi, off, 32));
    }
    const int x0 = (int)fminf(fmaxf(floorf(xlo), 0.0f), 512.0f);
    const int x1 = (int)fminf(fmaxf(ceilf(xhi), -1.0f), 511.0f);   // empty -> x0 > x1
    __syncthreads();

    // ---- pixel loop: 32 lanes cover this row's bbox ----
    float sum = 0.0f, cnt = 0.0f;
    const float* row = y_pred + (size_t)b * HW * HW + (size_t)(y0 + r) * HW;
    for (int px = x0 + lane; px <= x1; px += 32) {
        const float fx = (float)px;
        float lab = 0.0f;
        bool  valid = false;
        #pragma unroll
        for (int k = 0; k < NPTS; ++k) {
            float dx = fx - s_xc[r][k];
            if (dx * dx < s_lim[r][k]) { lab = s_lab[r][k]; valid = true; }  // last k wins
        }
        if (valid) {
            float l   = row[px];
            float bce = fmaxf(l, 0.0f) - l * lab + log1pf(expf(-fabsf(l)));
            sum += bce;
            cnt += 1.0f;
        }
    }

    // ---- block reduction: wave shuffle then 4-wave LDS combine ----
    #pragma unroll
    for (int off = 32; off > 0; off >>= 1) {
        sum += __shfl_down(sum, off, 64);
        cnt += __shfl_down(cnt, off, 64);
    }
    __shared__ float rs[4], rc[4];
    if ((tid & 63) == 0) { rs[tid >> 6] = sum; rc[tid >> 6] = cnt; }
    __syncthreads();
    if (tid == 0) {
        ws[blockIdx.x * 2 + 0] = rs[0] + rs[1] + rs[2] + rs[3];
        ws[blockIdx.x * 2 + 1] = rc[0] + rc[1] + rc[2] + rc[3];
    }

    // ---- grid-wide barrier, then block 0 finalizes ----
    __threadfence();
    cg::this_grid().sync();

    if (blockIdx.x == 0) {
        const float4* w4 = (const float4*)ws;     // 256 float4 = 1024 floats
        float4 v = w4[tid];                        // {S,C,S,C}
        float S = v.x + v.z;
        float C = v.y + v.w;
        #pragma unroll
        for (int off = 32; off > 0; off >>= 1) {
            S += __shfl_down(S, off, 64);
            C += __shfl_down(C, off, 64);
        }
        __shared__ float fs[4], fc[4];
        if ((tid & 63) == 0) { fs[tid >> 6] = S; fc[tid >> 6] = C; }
        __syncthreads();
        if (tid == 0) {
            float SS = fs[0] + fs[1] + fs[2] + fs[3];
            float CC = fc[0] + fc[1] + fc[2] + fc[3];
            out[0] = (CC > 0.0f) ? (SS / CC) : 0.0f;
        }
    }
}

extern "C" void kernel_launch(void* const* d_in, const int* in_sizes, int n_in,
                              void* d_out, int out_size, void* d_ws, size_t ws_size,
                              hipStream_t stream) {
    const float* y_pred       = (const float*)d_in[0];   // (8,1,512,512) f32
    const int*   point_labels = (const int*)d_in[1];     // (8,20) i32
    const float* point_coords = (const float*)d_in[2];   // (8,20,2) f32
    float*       out          = (float*)d_out;           // scalar f32
    float*       ws           = (float*)d_ws;            // 1024 floats, fully rewritten

    void* args[] = { (void*)&y_pred, (void*)&point_labels, (void*)&point_coords,
                     (void*)&ws, (void*)&out };
    hipLaunchCooperativeKernel((const void*)pce_coop_kernel,
                               dim3(NBLOCKS), dim3(256), args, 0, stream);
}

// Round 4
// 21.060 us; speedup vs baseline: 4.4366x; 4.4366x over previous
//
#include <hip/hip_runtime.h>
#include <math.h>

// B=8, N=20, H=W=512. loss = sum(bce*valid)/cnt where the last point n with
// exp(-d2/(2*5^2)) > 0.1 (<=> d2 < 50*ln10) defines the per-pixel label.
// Single dispatch: block partials + flag handshake; block 0 finalizes.

#define R2_THRESH 115.12925464970229f
#define HW 512
#define NPTS 20
#define ROWS_PER_BLOCK 8
#define NBLOCKS 512              // 8 batches * 64 row-chunks
#define MAGIC 0x5F3C9A17u

__global__ __launch_bounds__(256)
void pce_one_kernel(const float* __restrict__ y_pred,
                    const int* __restrict__ point_labels,
                    const float* __restrict__ point_coords,
                    float* __restrict__ ws,        // [1024] S/C pairs
                    unsigned* __restrict__ flags,  // [512], 0 on entry, 0 on exit
                    float* __restrict__ out) {
    const int b     = blockIdx.x >> 6;
    const int chunk = blockIdx.x & 63;
    const int y0    = chunk * ROWS_PER_BLOCK;
    const int tid   = threadIdx.x;
    const int r     = tid >> 5;               // 8 rows, 32 lanes each
    const int lane  = tid & 31;

    __shared__ float s_xc[ROWS_PER_BLOCK][NPTS];
    __shared__ float s_lim[ROWS_PER_BLOCK][NPTS];
    __shared__ float s_lab[ROWS_PER_BLOCK][NPTS];

    // ---- parallel setup: thread (r, n=lane<20) tests point n on row y0+r ----
    float xlo = INFINITY, xhi = -INFINITY;
    if (lane < NPTS) {
        const int n = lane;
        float yc  = point_coords[b * (NPTS * 2) + n * 2 + 0] * (float)HW;
        float xc  = point_coords[b * (NPTS * 2) + n * 2 + 1] * (float)HW;
        float dy  = (float)(y0 + r) - yc;
        float lim = R2_THRESH - dy * dy;
        s_xc[r][n]  = xc;
        s_lim[r][n] = lim;                    // lim<=0 -> dx*dx<lim never true
        s_lab[r][n] = (float)point_labels[b * NPTS + n];
        if (lim > 0.0f) {
            float s = sqrtf(lim);
            xlo = xc - s;
            xhi = xc + s;
        }
    }
    #pragma unroll
    for (int off = 16; off > 0; off >>= 1) {
        xlo = fminf(xlo, __shfl_xor(xlo, off, 32));
        xhi = fmaxf(xhi, __shfl_xor(xhi, off, 32));
    }
    const int x0 = (int)fminf(fmaxf(floorf(xlo), 0.0f), 512.0f);
    const int x1 = (int)fminf(fmaxf(ceilf(xhi), -1.0f), 511.0f);   // empty -> x0 > x1
    __syncthreads();

    // ---- pixel loop: 32 lanes cover this row's bbox ----
    float sum = 0.0f, cnt = 0.0f;
    const float* row = y_pred + (size_t)b * HW * HW + (size_t)(y0 + r) * HW;
    for (int px = x0 + lane; px <= x1; px += 32) {
        const float fx = (float)px;
        float lab = 0.0f;
        bool  valid = false;
        #pragma unroll
        for (int k = 0; k < NPTS; ++k) {
            float dx = fx - s_xc[r][k];
            if (dx * dx < s_lim[r][k]) { lab = s_lab[r][k]; valid = true; }  // last k wins
        }
        if (valid) {
            float l   = row[px];
            float bce = fmaxf(l, 0.0f) - l * lab + log1pf(expf(-fabsf(l)));
            sum += bce;
            cnt += 1.0f;
        }
    }

    // ---- block reduction ----
    #pragma unroll
    for (int off = 32; off > 0; off >>= 1) {
        sum += __shfl_down(sum, off, 64);
        cnt += __shfl_down(cnt, off, 64);
    }
    __shared__ float rs[4], rc[4];
    if ((tid & 63) == 0) { rs[tid >> 6] = sum; rc[tid >> 6] = cnt; }
    __syncthreads();
    if (tid == 0) {
        float S = rs[0] + rs[1] + rs[2] + rs[3];
        float C = rc[0] + rc[1] + rc[2] + rc[3];
        __hip_atomic_store(&ws[blockIdx.x * 2 + 0], S, __ATOMIC_RELAXED, __HIP_MEMORY_SCOPE_AGENT);
        __hip_atomic_store(&ws[blockIdx.x * 2 + 1], C, __ATOMIC_RELAXED, __HIP_MEMORY_SCOPE_AGENT);
        __hip_atomic_store(&flags[blockIdx.x], MAGIC, __ATOMIC_RELEASE, __HIP_MEMORY_SCOPE_AGENT);
    }
    if (blockIdx.x != 0) return;

    // ---- block 0: spin-wait on all 512 flags (each thread owns 2) ----
    {
        unsigned f1 = 0, f2 = 0;
        while (f1 != MAGIC || f2 != MAGIC) {
            if (f1 != MAGIC)
                f1 = __hip_atomic_load(&flags[tid],       __ATOMIC_ACQUIRE, __HIP_MEMORY_SCOPE_AGENT);
            if (f2 != MAGIC)
                f2 = __hip_atomic_load(&flags[tid + 256], __ATOMIC_ACQUIRE, __HIP_MEMORY_SCOPE_AGENT);
            if (f1 != MAGIC || f2 != MAGIC) __builtin_amdgcn_s_sleep(1);
        }
    }
    __syncthreads();

    // ---- finalize: fixed-order reduction of 512 pairs ----
    {
        float Sa = __hip_atomic_load(&ws[tid * 2 + 0],         __ATOMIC_RELAXED, __HIP_MEMORY_SCOPE_AGENT);
        float Ca = __hip_atomic_load(&ws[tid * 2 + 1],         __ATOMIC_RELAXED, __HIP_MEMORY_SCOPE_AGENT);
        float Sb = __hip_atomic_load(&ws[(tid + 256) * 2 + 0], __ATOMIC_RELAXED, __HIP_MEMORY_SCOPE_AGENT);
        float Cb = __hip_atomic_load(&ws[(tid + 256) * 2 + 1], __ATOMIC_RELAXED, __HIP_MEMORY_SCOPE_AGENT);
        float S = Sa + Sb;
        float C = Ca + Cb;
        #pragma unroll
        for (int off = 32; off > 0; off >>= 1) {
            S += __shfl_down(S, off, 64);
            C += __shfl_down(C, off, 64);
        }
        __shared__ float fs[4], fc[4];
        if ((tid & 63) == 0) { fs[tid >> 6] = S; fc[tid >> 6] = C; }
        __syncthreads();
        if (tid == 0) {
            float SS = fs[0] + fs[1] + fs[2] + fs[3];
            float CC = fc[0] + fc[1] + fc[2] + fc[3];
            out[0] = (CC > 0.0f) ? (SS / CC) : 0.0f;
        }
        __syncthreads();   // all reads of ws/flags done before clearing
        __hip_atomic_store(&flags[tid],       0u, __ATOMIC_RELAXED, __HIP_MEMORY_SCOPE_AGENT);
        __hip_atomic_store(&flags[tid + 256], 0u, __ATOMIC_RELAXED, __HIP_MEMORY_SCOPE_AGENT);
    }
}

extern "C" void kernel_launch(void* const* d_in, const int* in_sizes, int n_in,
                              void* d_out, int out_size, void* d_ws, size_t ws_size,
                              hipStream_t stream) {
    const float* y_pred       = (const float*)d_in[0];   // (8,1,512,512) f32
    const int*   point_labels = (const int*)d_in[1];     // (8,20) i32
    const float* point_coords = (const float*)d_in[2];   // (8,20,2) f32
    float*       out          = (float*)d_out;           // scalar f32
    float*       ws           = (float*)d_ws;            // partials: 1024 floats
    unsigned*    flags        = (unsigned*)((float*)d_ws + 1024);  // 512 u32

    pce_one_kernel<<<NBLOCKS, 256, 0, stream>>>(y_pred, point_labels, point_coords,
                                                ws, flags, out);
}